// Round 5
// baseline (89.974 us; speedup 1.0000x reference)
//
#include <hip/hip_runtime.h>
#include <math.h>

// DiagonalSSMKernel: out[d,h,l] = 2*Re( sum_n scaled_c[d,h,n] * exp(dt[h]*a[h,n]*l) )
// H=1024, N=32 poles, L=4096, 2 dirs. Output fp32 [2,1024,4096] = 33.5 MB.
//
// R5: inner loop is at its packed-issue floor (3 v_pk inst per (pole,l-pair),
// ~5.1us). The per-pole seed (exp+sincos+~16 VALU) scales with waves per
// (h,pole): BLOCK 256->128, CHUNK 16->32 halves it (~2.7->1.35us). At the
// resulting 2 waves/SIMD, per-pole LDS latency would be exposed -> register
// prefetch of pole n+1 during pole n's j-loop. Recurrence stride is now z^128.

typedef float v2f __attribute__((ext_vector_type(2)));

constexpr int H     = 1024;
constexpr int NP    = 32;
constexpr int L     = 4096;
constexpr int BLOCK = 128;
constexpr int CHUNK = 32;   // BLOCK * CHUNK == L

constexpr float  TWOPI    = 6.283185307179586f;
constexpr double INV2PI_D = 0.15915494309189535;

__global__ __launch_bounds__(BLOCK, 2)
void ssm_vand_kernel(const float* __restrict__ log_dt,
                     const float* __restrict__ log_a_real,
                     const float* __restrict__ a_imag,
                     const float* __restrict__ coeffs,
                     float* __restrict__ out)
{
    const int h = blockIdx.x;
    const int t = threadIdx.x;

    // pole[3n+0] = {dar, rate(rev/l), Re(z^128), Im(z^128)}
    // pole[3n+1] = {p=2*Re(z^128), q=|z^128|^2, 2*s0r, 2*s0i}
    // pole[3n+2] = {2*s1r, 2*s1i, 0, 0}
    __shared__ float4 pole[NP * 3];

    if (t < NP) {
        const int n = t;
        const float dtf = expf(log_dt[h]);
        const float ar  = -expf(log_a_real[h * NP + n]);
        const float ai  = a_imag[h * NP + n];
        const float dar = ar * dtf;
        const float dai = ai * dtf;

        // phase rate in revolutions (frac), fp64 once for exactness
        const double rate  = (double)ai * (double)dtf * INV2PI_D;
        const float  rhi   = (float)(rate - floor(rate));

        // z^128 (j-step between consecutive l's of one thread)
        const float e128 = expf(128.0f * dar);
        double r128 = 128.0 * rate;
        r128 -= floor(r128);
        float s128, c128;
        sincosf((float)r128 * TWOPI, &s128, &c128);
        const float zr = e128 * c128;
        const float zi = e128 * s128;

        // g = (exp(da) - 1) / a
        const float ed = expf(dar);
        float sd, cd;
        sincosf(dai, &sd, &cd);
        const float emr = ed * cd - 1.0f;
        const float emi = ed * sd;
        const float inv = 1.0f / (ar * ar + ai * ai);
        const float gr  = (emr * ar + emi * ai) * inv;
        const float gi  = (emi * ar - emr * ai) * inv;

        const float cr0 = coeffs[((0 * H + h) * NP + n) * 2 + 0];
        const float ci0 = coeffs[((0 * H + h) * NP + n) * 2 + 1];
        const float cr1 = coeffs[((1 * H + h) * NP + n) * 2 + 0];
        const float ci1 = coeffs[((1 * H + h) * NP + n) * 2 + 1];

        pole[n * 3 + 0] = make_float4(dar, rhi, zr, zi);
        pole[n * 3 + 1] = make_float4(2.0f * zr,
                                      zr * zr + zi * zi,
                                      2.0f * (cr0 * gr - ci0 * gi),
                                      2.0f * (cr0 * gi + ci0 * gr));
        pole[n * 3 + 2] = make_float4(2.0f * (cr1 * gr - ci1 * gi),
                                      2.0f * (cr1 * gi + ci1 * gr),
                                      0.0f, 0.0f);
    }
    __syncthreads();

    v2f acc[CHUNK];
    #pragma unroll
    for (int j = 0; j < CHUNK; ++j) acc[j] = (v2f){0.0f, 0.0f};

    const float lf = (float)t;   // start l < 128: no phase compensation needed

    // register prefetch of pole n+1 hides per-pole LDS latency at 2 waves/SIMD
    float4 pa = pole[0];
    float4 pb = pole[1];
    float4 pc = pole[2];

    #pragma unroll 1
    for (int n = 0; n < NP; ++n) {
        const int np1 = (n + 1 < NP) ? (n + 1) : n;
        const float4 qa = pole[np1 * 3 + 0];
        const float4 qb = pole[np1 * 3 + 1];
        const float4 qc = pole[np1 * 3 + 2];

        // w = exp(da * t) at l = t   (shared across dirs)
        const float mg = __expf(pa.x * lf);
        const float ph = pa.y * lf;
        const float rev = ph - floorf(ph);
        float s, c;
        __sincosf(rev * TWOPI, &s, &c);
        const float wr = mg * c;
        const float wi = mg * s;
        // w2 = w * z^128  (l = t + 128)
        const float wr2 = fmaf(wr, pa.z, -(wi * pa.w));
        const float wi2 = fmaf(wi, pa.z,  (wr * pa.w));

        // packed start states: lane = (dir0, dir1), 2.0 folded into s
        const v2f sr = {pb.z, pc.x};
        const v2f si = {pb.w, pc.y};
        const v2f p  = {pb.x, pb.x};
        const v2f q  = {pb.y, pb.y};

        v2f xp = __builtin_elementwise_fma(sr, (v2f){wr,  wr},  -(si * (v2f){wi,  wi}));
        v2f x  = __builtin_elementwise_fma(sr, (v2f){wr2, wr2}, -(si * (v2f){wi2, wi2}));

        acc[0] += xp;
        acc[1] += x;

        #pragma unroll
        for (int j = 2; j < CHUNK; ++j) {
            const v2f nx = __builtin_elementwise_fma(p, x, -(q * xp));
            acc[j] += nx;
            xp = x;
            x  = nx;
        }

        pa = qa; pb = qb; pc = qc;
    }

    float* o0 = out + (size_t)h * L + t;        // dir 0
    float* o1 = o0 + (size_t)H * L;             // dir 1
    #pragma unroll
    for (int j = 0; j < CHUNK; ++j) {
        o0[j * BLOCK] = acc[j].x;
        o1[j * BLOCK] = acc[j].y;
    }
}

extern "C" void kernel_launch(void* const* d_in, const int* in_sizes, int n_in,
                              void* d_out, int out_size, void* d_ws, size_t ws_size,
                              hipStream_t stream) {
    const float* log_dt     = (const float*)d_in[0];
    const float* log_a_real = (const float*)d_in[1];
    const float* a_imag     = (const float*)d_in[2];
    const float* coeffs     = (const float*)d_in[3];
    // d_in[4] = sequence_length (== 4096, compile-time constant here)
    float* out = (float*)d_out;

    ssm_vand_kernel<<<dim3(H), dim3(BLOCK), 0, stream>>>(
        log_dt, log_a_real, a_imag, coeffs, out);
}